// Round 1
// baseline (1353.283 us; speedup 1.0000x reference)
//
#include <hip/hip_runtime.h>

// Problem constants (from reference): B=8, T=2048, C=1024, H=64
#define Bq 8
#define Tq 2048
#define Cq 1024
#define Hq 64

// Workspace layout (float offsets). Total = 3*B*T*H + 2*B*T floats = ~12.7MB
#define QO 0
#define KO (Bq*Tq*Hq)
#define VO (2*Bq*Tq*Hq)
#define MO (3*Bq*Tq*Hq)
#define DO (3*Bq*Tq*Hq + Bq*Tq)

// ---------------------------------------------------------------------------
// Kernel A: q/k/v projections.  q = idx @ Wq^T etc.  (torch Linear layout:
// W is [H, C] row-major, y[bt,h] = sum_c idx[bt,c] * W[h,c])
// Block: 256 threads, handles 8 rows of idx (8*1024 floats = 32KB LDS).
// Thread (rb = tid>>6, h = tid&63) computes rows rb and rb+4 for all 3 mats.
// ---------------------------------------------------------------------------
__global__ __launch_bounds__(256) void qkv_kernel(
    const float* __restrict__ idx,
    const float* __restrict__ Wk,
    const float* __restrict__ Wq,
    const float* __restrict__ Wv,
    float* __restrict__ ws)
{
    __shared__ float s_idx[8 * Cq];  // 32KB
    const int tid = threadIdx.x;
    const long r0 = (long)blockIdx.x * 8;

    // Cooperative load: 8 rows = 2048 float4, 256 threads -> 8 each (coalesced)
    {
        const float4* src = (const float4*)(idx + r0 * Cq);
        float4* s4 = (float4*)s_idx;
        #pragma unroll
        for (int j = 0; j < 8; ++j)
            s4[j * 256 + tid] = src[j * 256 + tid];
    }
    __syncthreads();

    const int rb = tid >> 6;   // 0..3 (wave id)
    const int h  = tid & 63;
    const float4* wqp = (const float4*)(Wq + h * Cq);
    const float4* wkp = (const float4*)(Wk + h * Cq);
    const float4* wvp = (const float4*)(Wv + h * Cq);

    float aq[2] = {0.f, 0.f}, ak[2] = {0.f, 0.f}, av[2] = {0.f, 0.f};

    for (int c4 = 0; c4 < Cq / 4; ++c4) {
        const float4 wq4 = wqp[c4];
        const float4 wk4 = wkp[c4];
        const float4 wv4 = wvp[c4];
        #pragma unroll
        for (int i = 0; i < 2; ++i) {
            // LDS broadcast within each wave (rb uniform per wave)
            const float4 x = *(const float4*)&s_idx[(rb + i * 4) * Cq + c4 * 4];
            aq[i] += x.x * wq4.x + x.y * wq4.y + x.z * wq4.z + x.w * wq4.w;
            ak[i] += x.x * wk4.x + x.y * wk4.y + x.z * wk4.z + x.w * wk4.w;
            av[i] += x.x * wv4.x + x.y * wv4.y + x.z * wv4.z + x.w * wv4.w;
        }
    }
    #pragma unroll
    for (int i = 0; i < 2; ++i) {
        const long o = (r0 + rb + i * 4) * Hq + h;  // coalesced across h
        ws[QO + o] = aq[i];
        ws[KO + o] = ak[i];
        ws[VO + o] = av[i];
    }
}

// ---------------------------------------------------------------------------
// Kernel B: per-COLUMN softmax stats (reference softmaxes over axis=1 = query
// axis!). For column s: m_s = max_{t>=s} q_t.k_s, D_s = sum_{t>=s} exp(.-m_s).
// Block: 256 threads = 4 waves, 4 columns (one per wave). q staged in padded
// 64x65 LDS tiles shared by all 4 waves; lane = t index within tile.
// ---------------------------------------------------------------------------
__global__ __launch_bounds__(256) void stats_kernel(
    const float* __restrict__ wq,
    const float* __restrict__ wk,
    float* __restrict__ m_out,
    float* __restrict__ d_out)
{
    __shared__ float q_tile[64 * 65];  // +1 pad: lane*65+h -> conflict-free
    __shared__ float k4[4 * 64];
    const int tid  = threadIdx.x;
    const int lane = tid & 63;
    const int w    = tid >> 6;
    const int b  = blockIdx.x >> 9;          // T/4 = 512 blocks per batch
    const int s0 = (blockIdx.x & 511) * 4;
    const int s  = s0 + w;                   // this wave's column

    k4[tid] = wk[((long)b * Tq + s) * Hq + lane];

    float m = -1e30f, d = 0.f;
    const int st0 = s0 & ~63;
    for (int st = st0; st < Tq; st += 64) {
        // stage 64 q rows (coalesced float4 loads, padded scatter into LDS)
        const float4* src = (const float4*)(wq + ((long)b * Tq + st) * Hq);
        #pragma unroll
        for (int i = 0; i < 4; ++i) {
            const int e = i * 256 + tid;          // float4 index, coalesced
            const float4 f = src[e];
            const int r = e >> 4, col = (e & 15) << 2;
            float* dst = &q_tile[r * 65 + col];
            dst[0] = f.x; dst[1] = f.y; dst[2] = f.z; dst[3] = f.w;
        }
        __syncthreads();

        const int t = st + lane;
        if (t >= s) {
            const float* qr = &q_tile[lane * 65];
            const float* kk = &k4[w * 64];
            float dot = 0.f;
            #pragma unroll
            for (int hh = 0; hh < 64; ++hh) dot += qr[hh] * kk[hh];
            const float nm = fmaxf(m, dot);
            d = d * __expf(m - nm) + __expf(dot - nm);
            m = nm;
        }
        __syncthreads();
    }

    // merge 64 lanes' (m, d) online-softmax state
    #pragma unroll
    for (int off = 1; off < 64; off <<= 1) {
        const float m2 = __shfl_xor(m, off);
        const float d2 = __shfl_xor(d, off);
        const float nm = fmaxf(m, m2);
        d = d * __expf(m - nm) + d2 * __expf(m2 - nm);
        m = nm;
    }
    if (lane == 0) {
        m_out[b * Tq + s] = m;
        d_out[b * Tq + s] = d;
    }
}

// ---------------------------------------------------------------------------
// Kernel C: out[t,h] = sum_{s<=t} exp(q_t.k_s - m_s)/D_s * v[s,h]
// Block: 256 threads = 4 waves, 4 queries (one per wave). k/v staged in padded
// LDS tiles shared by 4 waves. Phase 1: lane = s (dot + weight, batched expf).
// Phase 2: lane = h (accumulate weights * v).
// ---------------------------------------------------------------------------
__global__ __launch_bounds__(256) void out_kernel(
    const float* __restrict__ wq,
    const float* __restrict__ wk,
    const float* __restrict__ wv,
    const float* __restrict__ m_in,
    const float* __restrict__ d_in,
    float* __restrict__ out)
{
    __shared__ float k_tile[64 * 65];
    __shared__ float v_tile[64 * 65];
    __shared__ float qt[4 * 64];
    __shared__ float mt[64], dt[64];
    __shared__ float wsm[4 * 64];
    const int tid  = threadIdx.x;
    const int lane = tid & 63;
    const int w    = tid >> 6;
    const int b  = blockIdx.x >> 9;
    const int t0 = (blockIdx.x & 511) * 4;
    const int t  = t0 + w;                  // this wave's query row

    qt[tid] = wq[((long)b * Tq + t) * Hq + lane];

    float acc = 0.f;
    const int ntiles = (t0 + 3) / 64 + 1;   // block-uniform
    for (int tile = 0; tile < ntiles; ++tile) {
        const int st = tile * 64;
        const float4* ksrc = (const float4*)(wk + ((long)b * Tq + st) * Hq);
        const float4* vsrc = (const float4*)(wv + ((long)b * Tq + st) * Hq);
        #pragma unroll
        for (int i = 0; i < 4; ++i) {
            const int e = i * 256 + tid;
            const int r = e >> 4, col = (e & 15) << 2;
            float4 f = ksrc[e];
            float* dst = &k_tile[r * 65 + col];
            dst[0] = f.x; dst[1] = f.y; dst[2] = f.z; dst[3] = f.w;
            f = vsrc[e];
            dst = &v_tile[r * 65 + col];
            dst[0] = f.x; dst[1] = f.y; dst[2] = f.z; dst[3] = f.w;
        }
        if (tid < 64)       mt[tid]      = m_in[b * Tq + st + tid];
        else if (tid < 128) dt[tid - 64] = d_in[b * Tq + st + tid - 64];
        __syncthreads();

        // Phase 1: lane = local s; one dot + one expf per lane
        const int s = st + lane;
        const float* kr = &k_tile[lane * 65];
        const float* qq = &qt[w * 64];
        float dot = 0.f;
        #pragma unroll
        for (int hh = 0; hh < 64; ++hh) dot += qq[hh] * kr[hh];
        float weight = 0.f;
        if (s <= t) weight = __expf(dot - mt[lane]) / dt[lane];
        wsm[w * 64 + lane] = weight;
        __syncthreads();

        // Phase 2: lane = h; acc[h] += sum_s w_s * v[s,h]
        const float* wsp = &wsm[w * 64];
        #pragma unroll
        for (int s2 = 0; s2 < 64; ++s2)
            acc += wsp[s2] * v_tile[s2 * 65 + lane];
        __syncthreads();
    }
    out[((long)b * Tq + t) * Hq + lane] = acc;
}

extern "C" void kernel_launch(void* const* d_in, const int* in_sizes, int n_in,
                              void* d_out, int out_size, void* d_ws, size_t ws_size,
                              hipStream_t stream)
{
    // setup_inputs() order: idx, Wk, Wq, Wv  (all fp32 per reference)
    const float* idx = (const float*)d_in[0];
    const float* Wk  = (const float*)d_in[1];
    const float* Wq  = (const float*)d_in[2];
    const float* Wv  = (const float*)d_in[3];
    float* ws  = (float*)d_ws;
    float* out = (float*)d_out;

    qkv_kernel<<<Bq * Tq / 8, 256, 0, stream>>>(idx, Wk, Wq, Wv, ws);
    stats_kernel<<<Bq * Tq / 4, 256, 0, stream>>>(ws + QO, ws + KO, ws + MO, ws + DO);
    out_kernel<<<Bq * Tq / 4, 256, 0, stream>>>(ws + QO, ws + KO, ws + VO,
                                                ws + MO, ws + DO, out);
}

// Round 2
// 464.344 us; speedup vs baseline: 2.9144x; 2.9144x over previous
//
#include <hip/hip_runtime.h>

// Problem constants: B=8, T=2048, C=1024, H=64
#define Bq 8
#define Tq 2048
#define Cq 1024
#define Hq 64

// Workspace float offsets: q, k, v [B*T*H] each, then m, d [B*T] each
#define QO 0
#define KO (Bq*Tq*Hq)
#define VO (2*Bq*Tq*Hq)
#define MO (3*Bq*Tq*Hq)
#define DO (3*Bq*Tq*Hq + Bq*Tq)

#define LD 68   // padded leading dim for 64-wide LDS tiles (272B rows: 16B-aligned, conflict-free-ish)

// ---------------------------------------------------------------------------
// Kernel A: qkv projections as a register-blocked GEMM.
// C[16384 x 192] = idx[16384 x 1024] @ [Wq|Wk|Wv]^T.  Block = 64 rows x all
// 192 cols; K-chunks of 64 staged transposed in LDS. Thread micro-tile:
// 4 rows x (4 cols per matrix x 3) = 48 accumulators; per k-step 4 b128 LDS
// reads + 48 FMA.
// ---------------------------------------------------------------------------
__global__ __launch_bounds__(256) void qkv_kernel(
    const float* __restrict__ idx,
    const float* __restrict__ Wk,
    const float* __restrict__ Wq,
    const float* __restrict__ Wv,
    float* __restrict__ ws)
{
    __shared__ float a_t[64 * LD];        // [k][r]
    __shared__ float w_t[3][64 * LD];     // [mat][k][h]
    const int tid = threadIdx.x;
    const int rg = tid >> 4;              // 0..15 row group (4 rows)
    const int cg = tid & 15;              // 0..15 col group (h-quad)
    const long r0 = (long)blockIdx.x * 64;

    float acc[3][4][4] = {};              // [mat][row][col]

    for (int c0 = 0; c0 < Cq; c0 += 64) {
        __syncthreads();
        // stage A tile transposed: a_t[k][r]
        #pragma unroll
        for (int i = 0; i < 4; ++i) {
            const int e = i * 256 + tid;
            const int r = e >> 4, j = e & 15;
            const float4 f = *(const float4*)&idx[(r0 + r) * Cq + c0 + 4 * j];
            a_t[(4*j+0)*LD + r] = f.x;
            a_t[(4*j+1)*LD + r] = f.y;
            a_t[(4*j+2)*LD + r] = f.z;
            a_t[(4*j+3)*LD + r] = f.w;
        }
        // stage W tiles transposed: w_t[m][k][h]  (m compile-time)
        #pragma unroll
        for (int m = 0; m < 3; ++m) {
            const float* Wsrc = (m == 0) ? Wq : ((m == 1) ? Wk : Wv);
            float* wt = &w_t[m][0];
            #pragma unroll
            for (int i = 0; i < 4; ++i) {
                const int e = i * 256 + tid;
                const int h = e >> 4, j = e & 15;
                const float4 f = *(const float4*)&Wsrc[h * Cq + c0 + 4 * j];
                wt[(4*j+0)*LD + h] = f.x;
                wt[(4*j+1)*LD + h] = f.y;
                wt[(4*j+2)*LD + h] = f.z;
                wt[(4*j+3)*LD + h] = f.w;
            }
        }
        __syncthreads();

        #pragma unroll 8
        for (int k = 0; k < 64; ++k) {
            const float4 a4 = *(const float4*)&a_t[k * LD + rg * 4];
            const float av[4] = {a4.x, a4.y, a4.z, a4.w};
            #pragma unroll
            for (int m = 0; m < 3; ++m) {
                const float4 b4 = *(const float4*)&w_t[m][k * LD + cg * 4];
                const float bv[4] = {b4.x, b4.y, b4.z, b4.w};
                #pragma unroll
                for (int rr = 0; rr < 4; ++rr)
                    #pragma unroll
                    for (int cc = 0; cc < 4; ++cc)
                        acc[m][rr][cc] += av[rr] * bv[cc];
            }
        }
    }

    // store: q, k, v at [r*64 + cg*4 .. +3]
    #pragma unroll
    for (int rr = 0; rr < 4; ++rr) {
        const long r = r0 + rg * 4 + rr;
        float4 o;
        o.x = acc[0][rr][0]; o.y = acc[0][rr][1]; o.z = acc[0][rr][2]; o.w = acc[0][rr][3];
        *(float4*)&ws[QO + r * Hq + cg * 4] = o;
        o.x = acc[1][rr][0]; o.y = acc[1][rr][1]; o.z = acc[1][rr][2]; o.w = acc[1][rr][3];
        *(float4*)&ws[KO + r * Hq + cg * 4] = o;
        o.x = acc[2][rr][0]; o.y = acc[2][rr][1]; o.z = acc[2][rr][2]; o.w = acc[2][rr][3];
        *(float4*)&ws[VO + r * Hq + cg * 4] = o;
    }
}

// ---------------------------------------------------------------------------
// Kernel B: per-COLUMN softmax stats (reference softmaxes over axis=1!).
// Block = (b, 64-column s-tile). Iterate 64x64 t-tiles (t >= s), GEMM-style
// dots, per-thread online (m,d) per column, merge via shuffle + LDS.
// ---------------------------------------------------------------------------
__global__ __launch_bounds__(256) void stats_kernel(
    const float* __restrict__ q,
    const float* __restrict__ k,
    float* __restrict__ m_out,
    float* __restrict__ d_out)
{
    __shared__ float kt[64 * LD];   // [h][s]
    __shared__ float qt[64 * LD];   // [h][t]
    __shared__ float red_m[4][64];
    __shared__ float red_d[4][64];
    const int tid = threadIdx.x;
    const int w  = tid >> 6;
    const int tg = tid >> 4;        // 0..15 (t quad)
    const int sg = tid & 15;        // 0..15 (s quad)
    const int b  = blockIdx.x >> 5;
    const int s0 = (blockIdx.x & 31) * 64;

    // stage K tile transposed: kt[h][s]
    #pragma unroll
    for (int i = 0; i < 4; ++i) {
        const int e = i * 256 + tid;
        const int s = e >> 4, j = e & 15;
        const float4 f = *(const float4*)&k[((long)b * Tq + s0 + s) * Hq + 4 * j];
        kt[(4*j+0)*LD + s] = f.x;
        kt[(4*j+1)*LD + s] = f.y;
        kt[(4*j+2)*LD + s] = f.z;
        kt[(4*j+3)*LD + s] = f.w;
    }

    float mloc[4] = {-1e30f, -1e30f, -1e30f, -1e30f};
    float dloc[4] = {0.f, 0.f, 0.f, 0.f};

    for (int t0 = s0; t0 < Tq; t0 += 64) {
        __syncthreads();
        #pragma unroll
        for (int i = 0; i < 4; ++i) {
            const int e = i * 256 + tid;
            const int r = e >> 4, j = e & 15;
            const float4 f = *(const float4*)&q[((long)b * Tq + t0 + r) * Hq + 4 * j];
            qt[(4*j+0)*LD + r] = f.x;
            qt[(4*j+1)*LD + r] = f.y;
            qt[(4*j+2)*LD + r] = f.z;
            qt[(4*j+3)*LD + r] = f.w;
        }
        __syncthreads();

        float dots[4][4] = {};
        #pragma unroll 8
        for (int h = 0; h < 64; ++h) {
            const float4 qa4 = *(const float4*)&qt[h * LD + tg * 4];
            const float4 kb4 = *(const float4*)&kt[h * LD + sg * 4];
            const float qa[4] = {qa4.x, qa4.y, qa4.z, qa4.w};
            const float kb[4] = {kb4.x, kb4.y, kb4.z, kb4.w};
            #pragma unroll
            for (int tt = 0; tt < 4; ++tt)
                #pragma unroll
                for (int ss = 0; ss < 4; ++ss)
                    dots[tt][ss] += qa[tt] * kb[ss];
        }

        if (t0 > s0) {
            // full tile: all t >= s
            #pragma unroll
            for (int ss = 0; ss < 4; ++ss) {
                float tm = fmaxf(fmaxf(dots[0][ss], dots[1][ss]),
                                 fmaxf(dots[2][ss], dots[3][ss]));
                const float nm = fmaxf(mloc[ss], tm);
                float sum = 0.f;
                #pragma unroll
                for (int tt = 0; tt < 4; ++tt)
                    sum += __expf(dots[tt][ss] - nm);
                dloc[ss] = dloc[ss] * __expf(mloc[ss] - nm) + sum;
                mloc[ss] = nm;
            }
        } else {
            // diagonal tile: per-element causal check
            #pragma unroll
            for (int ss = 0; ss < 4; ++ss) {
                const int s = s0 + sg * 4 + ss;
                #pragma unroll
                for (int tt = 0; tt < 4; ++tt) {
                    const int t = t0 + tg * 4 + tt;
                    if (t >= s) {
                        const float nm = fmaxf(mloc[ss], dots[tt][ss]);
                        dloc[ss] = dloc[ss] * __expf(mloc[ss] - nm) + __expf(dots[tt][ss] - nm);
                        mloc[ss] = nm;
                    }
                }
            }
        }
    }

    // merge across lanes sharing sg (xor bits 4,5 of lane = tg-within-wave)
    #pragma unroll
    for (int off = 16; off < 64; off <<= 1) {
        #pragma unroll
        for (int ss = 0; ss < 4; ++ss) {
            const float m2 = __shfl_xor(mloc[ss], off);
            const float d2 = __shfl_xor(dloc[ss], off);
            const float nm = fmaxf(mloc[ss], m2);
            dloc[ss] = dloc[ss] * __expf(mloc[ss] - nm) + d2 * __expf(m2 - nm);
            mloc[ss] = nm;
        }
    }
    if ((tid & 63) < 16) {
        #pragma unroll
        for (int ss = 0; ss < 4; ++ss) {
            red_m[w][sg * 4 + ss] = mloc[ss];
            red_d[w][sg * 4 + ss] = dloc[ss];
        }
    }
    __syncthreads();
    if (tid < 64) {
        float m = red_m[0][tid], d = red_d[0][tid];
        #pragma unroll
        for (int ww = 1; ww < 4; ++ww) {
            const float m2 = red_m[ww][tid], d2 = red_d[ww][tid];
            const float nm = fmaxf(m, m2);
            d = d * __expf(m - nm) + d2 * __expf(m2 - nm);
            m = nm;
        }
        m_out[b * Tq + s0 + tid] = m;
        d_out[b * Tq + s0 + tid] = d;
    }
}

// ---------------------------------------------------------------------------
// Kernel C: out[t][h] = sum_{s<=t} exp(q_t.k_s - m_s)/D_s * v[s][h]
// Block = (b, 64-row t-tile). Per s-tile: dot GEMM -> weights -> wT in LDS ->
// PV GEMM into persistent 4x4 O micro-tile.
// ---------------------------------------------------------------------------
__global__ __launch_bounds__(256) void out_kernel(
    const float* __restrict__ q,
    const float* __restrict__ k,
    const float* __restrict__ v,
    const float* __restrict__ m_in,
    const float* __restrict__ d_in,
    float* __restrict__ out)
{
    __shared__ float qt[64 * LD];   // [h][t]
    __shared__ float kt[64 * LD];   // [h][s]
    __shared__ float vt[64 * LD];   // [s][h]
    __shared__ float wT[64 * LD];   // [s][t]
    __shared__ float mt[64], rdt[64];
    const int tid = threadIdx.x;
    const int tg = tid >> 4;        // t quad
    const int sg = tid & 15;        // s quad (dot phase) / h quad (PV + store)
    const int b  = blockIdx.x >> 5;
    const int t0 = (blockIdx.x & 31) * 64;

    // stage Q tile transposed (once)
    #pragma unroll
    for (int i = 0; i < 4; ++i) {
        const int e = i * 256 + tid;
        const int r = e >> 4, j = e & 15;
        const float4 f = *(const float4*)&q[((long)b * Tq + t0 + r) * Hq + 4 * j];
        qt[(4*j+0)*LD + r] = f.x;
        qt[(4*j+1)*LD + r] = f.y;
        qt[(4*j+2)*LD + r] = f.z;
        qt[(4*j+3)*LD + r] = f.w;
    }

    float oacc[4][4] = {};          // [tt][hh]

    for (int s0 = 0; s0 <= t0; s0 += 64) {
        __syncthreads();
        // stage K tile transposed
        #pragma unroll
        for (int i = 0; i < 4; ++i) {
            const int e = i * 256 + tid;
            const int s = e >> 4, j = e & 15;
            const float4 f = *(const float4*)&k[((long)b * Tq + s0 + s) * Hq + 4 * j];
            kt[(4*j+0)*LD + s] = f.x;
            kt[(4*j+1)*LD + s] = f.y;
            kt[(4*j+2)*LD + s] = f.z;
            kt[(4*j+3)*LD + s] = f.w;
        }
        // stage V tile (row-major, vectorized LDS write)
        #pragma unroll
        for (int i = 0; i < 4; ++i) {
            const int e = i * 256 + tid;
            const int s = e >> 4, j = e & 15;
            const float4 f = *(const float4*)&v[((long)b * Tq + s0 + s) * Hq + 4 * j];
            *(float4*)&vt[s * LD + 4 * j] = f;
        }
        if (tid < 64) {
            mt[tid]  = m_in[b * Tq + s0 + tid];
            rdt[tid] = 1.0f / d_in[b * Tq + s0 + tid];
        }
        __syncthreads();

        // dot GEMM
        float dots[4][4] = {};
        #pragma unroll 8
        for (int h = 0; h < 64; ++h) {
            const float4 qa4 = *(const float4*)&qt[h * LD + tg * 4];
            const float4 kb4 = *(const float4*)&kt[h * LD + sg * 4];
            const float qa[4] = {qa4.x, qa4.y, qa4.z, qa4.w};
            const float kb[4] = {kb4.x, kb4.y, kb4.z, kb4.w};
            #pragma unroll
            for (int tt = 0; tt < 4; ++tt)
                #pragma unroll
                for (int ss = 0; ss < 4; ++ss)
                    dots[tt][ss] += qa[tt] * kb[ss];
        }

        // weights -> wT[s][t]
        const bool diag = (s0 == t0);
        #pragma unroll
        for (int ss = 0; ss < 4; ++ss) {
            const int sl = sg * 4 + ss;
            const float mv = mt[sl];
            const float rv = rdt[sl];
            #pragma unroll
            for (int tt = 0; tt < 4; ++tt) {
                float wgt = __expf(dots[tt][ss] - mv) * rv;
                if (diag && (tg * 4 + tt < sl)) wgt = 0.f;
                wT[sl * LD + tg * 4 + tt] = wgt;
            }
        }
        __syncthreads();

        // PV GEMM: oacc[tt][hh] += wT[s][t] * vt[s][h]
        #pragma unroll 8
        for (int s = 0; s < 64; ++s) {
            const float4 wv4 = *(const float4*)&wT[s * LD + tg * 4];
            const float4 vv4 = *(const float4*)&vt[s * LD + sg * 4];
            const float wv[4] = {wv4.x, wv4.y, wv4.z, wv4.w};
            const float vv[4] = {vv4.x, vv4.y, vv4.z, vv4.w};
            #pragma unroll
            for (int tt = 0; tt < 4; ++tt)
                #pragma unroll
                for (int hh = 0; hh < 4; ++hh)
                    oacc[tt][hh] += wv[tt] * vv[hh];
        }
    }

    #pragma unroll
    for (int tt = 0; tt < 4; ++tt) {
        float4 o;
        o.x = oacc[tt][0]; o.y = oacc[tt][1]; o.z = oacc[tt][2]; o.w = oacc[tt][3];
        *(float4*)&out[((long)b * Tq + t0 + tg * 4 + tt) * Hq + sg * 4] = o;
    }
}

extern "C" void kernel_launch(void* const* d_in, const int* in_sizes, int n_in,
                              void* d_out, int out_size, void* d_ws, size_t ws_size,
                              hipStream_t stream)
{
    const float* idx = (const float*)d_in[0];
    const float* Wk  = (const float*)d_in[1];
    const float* Wq  = (const float*)d_in[2];
    const float* Wv  = (const float*)d_in[3];
    float* ws  = (float*)d_ws;
    float* out = (float*)d_out;

    qkv_kernel<<<Bq * Tq / 64, 256, 0, stream>>>(idx, Wk, Wq, Wv, ws);
    stats_kernel<<<Bq * (Tq / 64), 256, 0, stream>>>(ws + QO, ws + KO, ws + MO, ws + DO);
    out_kernel<<<Bq * (Tq / 64), 256, 0, stream>>>(ws + QO, ws + KO, ws + VO,
                                                   ws + MO, ws + DO, out);
}

// Round 3
// 334.168 us; speedup vs baseline: 4.0497x; 1.3896x over previous
//
#include <hip/hip_runtime.h>

// Problem constants: B=8, T=2048, C=1024, H=64
#define Bq 8
#define Tq 2048
#define Cq 1024
#define Hq 64

// ws float offsets: qT [B][H][T], kT [B][H][T], v [B][T][H], D [B][T]
#define QT_OFF 0
#define KT_OFF (Bq*Hq*Tq)
#define VV_OFF (2*Bq*Hq*Tq)
#define DD_OFF (3*Bq*Hq*Tq)

#define LDW 68   // 64-col LDS tiles, padded (272B rows, 16B aligned)
#define LDA 36   // 32-col LDS tile for qkv A

// ---------------------------------------------------------------------------
// Kernel A: qkv projections. 32-row tiles (512 blocks -> 2/CU).
// Writes q,k TRANSPOSED ([B][H][T]) so downstream kernels never transpose;
// v row-major. LDS staging transposes use XOR swizzle (2-way banks = free).
// ---------------------------------------------------------------------------
__global__ __launch_bounds__(256) void qkv_kernel(
    const float* __restrict__ idx,
    const float* __restrict__ Wk,
    const float* __restrict__ Wq,
    const float* __restrict__ Wv,
    float* __restrict__ qT,
    float* __restrict__ kT,
    float* __restrict__ vv)
{
    __shared__ float a_t[64 * LDA];       // [k][r] swizzled
    __shared__ float w_t[3][64 * LDW];    // [mat][k][h] swizzled
    const int tid = threadIdx.x;
    const int rg2 = tid >> 4;             // 0..15 -> rows 2*rg2, 2*rg2+1
    const int cg  = tid & 15;             // h quad
    const int r0 = blockIdx.x * 32;
    const int b  = r0 >> 11;
    const int t0 = r0 & 2047;

    float acc[3][2][4] = {};

    for (int c0 = 0; c0 < Cq; c0 += 64) {
        __syncthreads();
        // stage A transposed+swizzled: element (k=c-local, r) at
        // k*LDA + 4*((r>>2)^((k>>2)&7)) + (r&3)
        #pragma unroll
        for (int i = 0; i < 2; ++i) {
            const int e = i * 256 + tid;
            const int r = e >> 4, j = e & 15;
            const float4 f = *(const float4*)&idx[(long)(r0 + r) * Cq + c0 + 4 * j];
            const int sw = 4 * ((r >> 2) ^ (j & 7)) + (r & 3);
            a_t[(4*j+0)*LDA + sw] = f.x;
            a_t[(4*j+1)*LDA + sw] = f.y;
            a_t[(4*j+2)*LDA + sw] = f.z;
            a_t[(4*j+3)*LDA + sw] = f.w;
        }
        // stage W transposed+swizzled: (k, h) at k*LDW + 4*((h>>2)^((k>>2)&7)) + (h&3)
        #pragma unroll
        for (int m = 0; m < 3; ++m) {
            const float* Wsrc = (m == 0) ? Wq : ((m == 1) ? Wk : Wv);
            float* wt = &w_t[m][0];
            #pragma unroll
            for (int i = 0; i < 4; ++i) {
                const int e = i * 256 + tid;
                const int h = e >> 4, j = e & 15;
                const float4 f = *(const float4*)&Wsrc[(long)h * Cq + c0 + 4 * j];
                const int sw = 4 * ((h >> 2) ^ (j & 7)) + (h & 3);
                wt[(4*j+0)*LDW + sw] = f.x;
                wt[(4*j+1)*LDW + sw] = f.y;
                wt[(4*j+2)*LDW + sw] = f.z;
                wt[(4*j+3)*LDW + sw] = f.w;
            }
        }
        __syncthreads();

        #pragma unroll 8
        for (int k = 0; k < 64; ++k) {
            const int f = (k >> 2) & 7;
            const float2 a2 = *(const float2*)&a_t[k * LDA + 4 * ((rg2 >> 1) ^ f) + 2 * (rg2 & 1)];
            #pragma unroll
            for (int m = 0; m < 3; ++m) {
                const float4 b4 = *(const float4*)&w_t[m][k * LDW + 4 * (cg ^ f)];
                const float bv[4] = {b4.x, b4.y, b4.z, b4.w};
                #pragma unroll
                for (int cc = 0; cc < 4; ++cc) {
                    acc[m][0][cc] += a2.x * bv[cc];
                    acc[m][1][cc] += a2.y * bv[cc];
                }
            }
        }
    }

    const int tl = t0 + 2 * rg2;
    #pragma unroll
    for (int cc = 0; cc < 4; ++cc) {
        const int h = 4 * cg + cc;
        float2 o;
        o.x = acc[0][0][cc]; o.y = acc[0][1][cc];
        *(float2*)&qT[(long)(b * Hq + h) * Tq + tl] = o;
        o.x = acc[1][0][cc]; o.y = acc[1][1][cc];
        *(float2*)&kT[(long)(b * Hq + h) * Tq + tl] = o;
    }
    #pragma unroll
    for (int rr = 0; rr < 2; ++rr) {
        float4 o;
        o.x = acc[2][rr][0]; o.y = acc[2][rr][1]; o.z = acc[2][rr][2]; o.w = acc[2][rr][3];
        *(float4*)&vv[(long)(b * Tq + tl + rr) * Hq + 4 * cg] = o;
    }
}

// ---------------------------------------------------------------------------
// Kernel B: column denominators. D_s = sum_{t>=s} exp(q_t.k_s)  (no max:
// dots ~ N(0,3.3), |dot| << 88, fp32 exp safe). Grid: (80 chunk-units, B).
// Block = (s-tile i, t-chunk c of <=8 t-tiles); atomicAdd partial sums.
// ---------------------------------------------------------------------------
__global__ __launch_bounds__(256) void stats_kernel(
    const float* __restrict__ qT,
    const float* __restrict__ kT,
    float* __restrict__ D)
{
    __shared__ float kt[64 * LDW];   // [h][s]
    __shared__ float qt[64 * LDW];   // [h][t]
    __shared__ float red[4][64];
    const int tid = threadIdx.x;
    const int tg = tid >> 4;         // t quad
    const int sg = tid & 15;         // s quad
    const int w  = tid >> 6;
    const int b  = blockIdx.y;

    int x = blockIdx.x, i = 0;
    for (;;) { const int nc = (39 - i) >> 3; if (x < nc) break; x -= nc; ++i; }
    const int c = x;
    const int s0 = i * 64;

    // stage K tile (direct copy: conflict-free float4)
    #pragma unroll
    for (int ii = 0; ii < 4; ++ii) {
        const int e = ii * 256 + tid;
        const int h = e >> 4, j = e & 15;
        *(float4*)&kt[h * LDW + 4 * j] =
            *(const float4*)&kT[(long)(b * Hq + h) * Tq + s0 + 4 * j];
    }

    float dsum[4] = {0.f, 0.f, 0.f, 0.f};
    const int jt1 = min(i + 8 * c + 8, 32);
    for (int jt = i + 8 * c; jt < jt1; ++jt) {
        const int tt0 = jt * 64;
        __syncthreads();
        #pragma unroll
        for (int ii = 0; ii < 4; ++ii) {
            const int e = ii * 256 + tid;
            const int h = e >> 4, j = e & 15;
            *(float4*)&qt[h * LDW + 4 * j] =
                *(const float4*)&qT[(long)(b * Hq + h) * Tq + tt0 + 4 * j];
        }
        __syncthreads();

        float dots[4][4] = {};
        #pragma unroll 8
        for (int h = 0; h < 64; ++h) {
            const float4 qa4 = *(const float4*)&qt[h * LDW + 4 * tg];
            const float4 kb4 = *(const float4*)&kt[h * LDW + 4 * sg];
            const float qa[4] = {qa4.x, qa4.y, qa4.z, qa4.w};
            const float kb[4] = {kb4.x, kb4.y, kb4.z, kb4.w};
            #pragma unroll
            for (int tt = 0; tt < 4; ++tt)
                #pragma unroll
                for (int ss = 0; ss < 4; ++ss)
                    dots[tt][ss] += qa[tt] * kb[ss];
        }

        if (jt > i) {
            #pragma unroll
            for (int ss = 0; ss < 4; ++ss)
                #pragma unroll
                for (int tt = 0; tt < 4; ++tt)
                    dsum[ss] += __expf(dots[tt][ss]);
        } else {
            #pragma unroll
            for (int ss = 0; ss < 4; ++ss) {
                const int sl = 4 * sg + ss;
                #pragma unroll
                for (int tt = 0; tt < 4; ++tt)
                    if (4 * tg + tt >= sl) dsum[ss] += __expf(dots[tt][ss]);
            }
        }
    }

    #pragma unroll
    for (int ss = 0; ss < 4; ++ss) {
        dsum[ss] += __shfl_xor(dsum[ss], 16);
        dsum[ss] += __shfl_xor(dsum[ss], 32);
    }
    if ((tid & 63) < 16)
        #pragma unroll
        for (int ss = 0; ss < 4; ++ss) red[w][4 * sg + ss] = dsum[ss];
    __syncthreads();
    if (tid < 64) {
        const float t = red[0][tid] + red[1][tid] + red[2][tid] + red[3][tid];
        atomicAdd(&D[b * Tq + s0 + tid], t);
    }
}

// ---------------------------------------------------------------------------
// Kernel C: out[t][h] = sum_{s<=t} exp(q_t.k_s)/D_s * v[s][h]
// Grid: (80 chunk-units, B). Block = (t-tile i, s-chunk c). kt buffer reused
// for wT. Single-chunk tiles (i<8) store directly; others atomicAdd.
// ---------------------------------------------------------------------------
__global__ __launch_bounds__(256) void out_kernel(
    const float* __restrict__ qT,
    const float* __restrict__ kT,
    const float* __restrict__ vv,
    const float* __restrict__ D,
    float* __restrict__ out)
{
    __shared__ float qt[64 * LDW];    // [h][t]
    __shared__ float ktw[64 * LDW];   // [h][s] then reused as wT [s][t]
    __shared__ float vt[64 * LDW];    // [s][h]
    __shared__ float rdt[64];
    const int tid = threadIdx.x;
    const int tg = tid >> 4;
    const int sg = tid & 15;
    const int b  = blockIdx.y;

    int x = blockIdx.x, i = 0;
    for (;;) { const int nc = (i + 8) >> 3; if (x < nc) break; x -= nc; ++i; }
    const int c = x;
    const int t0 = i * 64;

    #pragma unroll
    for (int ii = 0; ii < 4; ++ii) {
        const int e = ii * 256 + tid;
        const int h = e >> 4, j = e & 15;
        *(float4*)&qt[h * LDW + 4 * j] =
            *(const float4*)&qT[(long)(b * Hq + h) * Tq + t0 + 4 * j];
    }

    float oacc[4][4] = {};
    const int js1 = min(8 * c + 8, i + 1);
    for (int js = 8 * c; js < js1; ++js) {
        const int s0 = js * 64;
        __syncthreads();
        #pragma unroll
        for (int ii = 0; ii < 4; ++ii) {
            const int e = ii * 256 + tid;
            const int h = e >> 4, j = e & 15;
            *(float4*)&ktw[h * LDW + 4 * j] =
                *(const float4*)&kT[(long)(b * Hq + h) * Tq + s0 + 4 * j];
            *(float4*)&vt[h * LDW + 4 * j] =
                *(const float4*)&vv[(long)(b * Tq + s0 + h) * Hq + 4 * j];
        }
        if (tid < 64) rdt[tid] = 1.0f / D[b * Tq + s0 + tid];
        __syncthreads();

        float dots[4][4] = {};
        #pragma unroll 8
        for (int h = 0; h < 64; ++h) {
            const float4 qa4 = *(const float4*)&qt[h * LDW + 4 * tg];
            const float4 kb4 = *(const float4*)&ktw[h * LDW + 4 * sg];
            const float qa[4] = {qa4.x, qa4.y, qa4.z, qa4.w};
            const float kb[4] = {kb4.x, kb4.y, kb4.z, kb4.w};
            #pragma unroll
            for (int tt = 0; tt < 4; ++tt)
                #pragma unroll
                for (int ss = 0; ss < 4; ++ss)
                    dots[tt][ss] += qa[tt] * kb[ss];
        }
        __syncthreads();   // done reading ktw as K

        const bool diag = (js == i);
        #pragma unroll
        for (int ss = 0; ss < 4; ++ss) {
            const int sl = 4 * sg + ss;
            const float rv = rdt[sl];
            float4 w4;
            float wv[4];
            #pragma unroll
            for (int tt = 0; tt < 4; ++tt) {
                float wgt = __expf(dots[tt][ss]) * rv;
                if (diag && (4 * tg + tt < sl)) wgt = 0.f;
                wv[tt] = wgt;
            }
            w4.x = wv[0]; w4.y = wv[1]; w4.z = wv[2]; w4.w = wv[3];
            *(float4*)&ktw[sl * LDW + 4 * tg] = w4;   // wT [s][t]
        }
        __syncthreads();

        #pragma unroll 8
        for (int s = 0; s < 64; ++s) {
            const float4 wv4 = *(const float4*)&ktw[s * LDW + 4 * tg];
            const float4 vv4 = *(const float4*)&vt[s * LDW + 4 * sg];
            const float wv[4] = {wv4.x, wv4.y, wv4.z, wv4.w};
            const float vb[4] = {vv4.x, vv4.y, vv4.z, vv4.w};
            #pragma unroll
            for (int tt = 0; tt < 4; ++tt)
                #pragma unroll
                for (int hh = 0; hh < 4; ++hh)
                    oacc[tt][hh] += wv[tt] * vb[hh];
        }
    }

    const bool single = (i < 8);   // only one s-chunk -> exclusive writer
    #pragma unroll
    for (int tt = 0; tt < 4; ++tt) {
        const long o = (long)(b * Tq + t0 + 4 * tg + tt) * Hq + 4 * sg;
        if (single) {
            float4 ov;
            ov.x = oacc[tt][0]; ov.y = oacc[tt][1]; ov.z = oacc[tt][2]; ov.w = oacc[tt][3];
            *(float4*)&out[o] = ov;
        } else {
            atomicAdd(&out[o + 0], oacc[tt][0]);
            atomicAdd(&out[o + 1], oacc[tt][1]);
            atomicAdd(&out[o + 2], oacc[tt][2]);
            atomicAdd(&out[o + 3], oacc[tt][3]);
        }
    }
}

extern "C" void kernel_launch(void* const* d_in, const int* in_sizes, int n_in,
                              void* d_out, int out_size, void* d_ws, size_t ws_size,
                              hipStream_t stream)
{
    const float* idx = (const float*)d_in[0];
    const float* Wk  = (const float*)d_in[1];
    const float* Wq  = (const float*)d_in[2];
    const float* Wv  = (const float*)d_in[3];
    float* ws  = (float*)d_ws;
    float* out = (float*)d_out;

    hipMemsetAsync(out, 0, (size_t)Bq * Tq * Hq * sizeof(float), stream);
    hipMemsetAsync(ws + DD_OFF, 0, (size_t)Bq * Tq * sizeof(float), stream);

    qkv_kernel<<<Bq * Tq / 32, 256, 0, stream>>>(idx, Wk, Wq, Wv,
                                                 ws + QT_OFF, ws + KT_OFF, ws + VV_OFF);
    stats_kernel<<<dim3(80, Bq), 256, 0, stream>>>(ws + QT_OFF, ws + KT_OFF, ws + DD_OFF);
    out_kernel<<<dim3(80, Bq), 256, 0, stream>>>(ws + QT_OFF, ws + KT_OFF, ws + VV_OFF,
                                                 ws + DD_OFF, out);
}

// Round 4
// 199.928 us; speedup vs baseline: 6.7689x; 1.6714x over previous
//
#include <hip/hip_runtime.h>

// B=8, T=2048, C=1024, H=64.  Reference: softmax over QUERY axis (dim=1),
// no 1/sqrt(d) scale.  out[t,h] = sum_{s<=t} exp(q_t.k_s)/D_s * v[s,h],
// D_s = sum_{t>=s} exp(q_t.k_s).
//
// Numerics: split-bf16 (hi+lo) MFMA for qkv GEMM and all QK dots -> ~fp32
// accuracy; plain bf16 for V and softmax weights in PV (~0.4% rel).

typedef __attribute__((ext_vector_type(8))) short bf16x8;
typedef __attribute__((ext_vector_type(4))) float f32x4;
typedef unsigned short u16;

#define MFMA(a, b, c) __builtin_amdgcn_mfma_f32_16x16x32_bf16((a), (b), (c), 0, 0, 0)

__device__ __forceinline__ u16 f2bf(float x) {           // RNE fp32 -> bf16
    unsigned u = __float_as_uint(x);
    u += 0x7fff + ((u >> 16) & 1);
    return (u16)(u >> 16);
}
__device__ __forceinline__ float bf2f(u16 h) {
    return __uint_as_float(((unsigned)h) << 16);
}

// ws byte offsets
#define WH_OFF 0u
#define WL_OFF (WH_OFF + 192u*1024u*2u)
#define QH_OFF (WL_OFF + 192u*1024u*2u)
#define QL_OFF (QH_OFF + 8u*2048u*64u*2u)
#define KH_OFF (QL_OFF + 8u*2048u*64u*2u)
#define KL_OFF (KH_OFF + 8u*2048u*64u*2u)
#define VT_OFF (KL_OFF + 8u*2048u*64u*2u)
#define DD_OFF (VT_OFF + 8u*2048u*64u*2u)   // fp32 [B][T]

// ---------------------------------------------------------------------------
// W pre-split: rows 0..63 = Wq, 64..127 = Wk, 128..191 = Wv (matches qkv N map)
// ---------------------------------------------------------------------------
__global__ __launch_bounds__(256) void wsplit_kernel(
    const float* __restrict__ Wk, const float* __restrict__ Wq,
    const float* __restrict__ Wv, u16* __restrict__ WH, u16* __restrict__ WL)
{
    const int n = blockIdx.x;
    const float* src = (n < 64) ? (Wq + (long)n * 1024)
                     : (n < 128) ? (Wk + (long)(n - 64) * 1024)
                                 : (Wv + (long)(n - 128) * 1024);
    const float4 f = ((const float4*)src)[threadIdx.x];
    const float v[4] = {f.x, f.y, f.z, f.w};
    u16 hi[4], lo[4];
    #pragma unroll
    for (int j = 0; j < 4; ++j) {
        hi[j] = f2bf(v[j]);
        lo[j] = f2bf(v[j] - bf2f(hi[j]));
    }
    *(ushort4*)&WH[(long)n * 1024 + 4 * threadIdx.x] = make_ushort4(hi[0], hi[1], hi[2], hi[3]);
    *(ushort4*)&WL[(long)n * 1024 + 4 * threadIdx.x] = make_ushort4(lo[0], lo[1], lo[2], lo[3]);
}

// ---------------------------------------------------------------------------
// qkv: [16384x1024] @ [1024x192] via split-bf16 MFMA.  M-tile 32 (512 blocks).
// LDS rows: [k_hi 32 | k_lo 32 | pad 8] bf16 (144B rows -> 2-way banks = free).
// Wave w: m-frag (w&1), n-frags (w>>1)*6 .. +5.  Outputs qh/ql/kh/kl [B][T][H],
// vT [B][H][T] bf16.
// ---------------------------------------------------------------------------
__global__ __launch_bounds__(256) void qkv_kernel(
    const float* __restrict__ idx, const u16* __restrict__ WH, const u16* __restrict__ WL,
    u16* __restrict__ QH, u16* __restrict__ QL,
    u16* __restrict__ KH, u16* __restrict__ KL, u16* __restrict__ VT)
{
    __shared__ u16 a_l[32 * 72];
    __shared__ u16 w_l[192 * 72];
    const int tid = threadIdx.x;
    const int w = tid >> 6, lr = tid & 15, quad = (tid >> 4) & 3;
    const int r0 = blockIdx.x * 32;
    const int b = r0 >> 11, t0 = r0 & 2047;
    const int m0 = (w & 1) * 16;
    const int nb = (w >> 1) * 96;

    f32x4 acc[6] = {};

    for (int c0 = 0; c0 < 1024; c0 += 32) {
        __syncthreads();
        {   // A stage + split: 32 rows x 32 cols fp32
            const int r = tid >> 3, c4 = tid & 7;
            const float4 f = *(const float4*)&idx[(long)(r0 + r) * 1024 + c0 + 4 * c4];
            const float v[4] = {f.x, f.y, f.z, f.w};
            u16 hi[4], lo[4];
            #pragma unroll
            for (int j = 0; j < 4; ++j) {
                hi[j] = f2bf(v[j]);
                lo[j] = f2bf(v[j] - bf2f(hi[j]));
            }
            *(ushort4*)&a_l[r * 72 + 4 * c4]      = make_ushort4(hi[0], hi[1], hi[2], hi[3]);
            *(ushort4*)&a_l[r * 72 + 32 + 4 * c4] = make_ushort4(lo[0], lo[1], lo[2], lo[3]);
        }
        #pragma unroll
        for (int it = 0; it < 3; ++it) {   // W stage: 192 rows x 32 bf16 (x2)
            const int e = it * 256 + tid;
            const int n = e >> 2, c8 = e & 3;
            *(float4*)&w_l[n * 72 + 8 * c8]      = *(const float4*)&WH[(long)n * 1024 + c0 + 8 * c8];
            *(float4*)&w_l[n * 72 + 32 + 8 * c8] = *(const float4*)&WL[(long)n * 1024 + c0 + 8 * c8];
        }
        __syncthreads();

        const bf16x8 ah = *(const bf16x8*)&a_l[(m0 + lr) * 72 + quad * 8];
        const bf16x8 al = *(const bf16x8*)&a_l[(m0 + lr) * 72 + 32 + quad * 8];
        #pragma unroll
        for (int nf = 0; nf < 6; ++nf) {
            const int br = (nb + nf * 16 + lr) * 72 + quad * 8;
            const bf16x8 bh = *(const bf16x8*)&w_l[br];
            const bf16x8 bl = *(const bf16x8*)&w_l[br + 32];
            acc[nf] = MFMA(ah, bh, acc[nf]);
            acc[nf] = MFMA(ah, bl, acc[nf]);
            acc[nf] = MFMA(al, bh, acc[nf]);
        }
    }

    // epilogue: C layout col = lane&15 (n), row = quad*4 + reg (m)
    const int tbase = t0 + m0 + quad * 4;
    #pragma unroll
    for (int nf = 0; nf < 6; ++nf) {
        const int n = nb + nf * 16 + lr;
        if (n < 128) {
            u16* Hd = (n < 64) ? QH : KH;
            u16* Ld = (n < 64) ? QL : KL;
            const int h = n & 63;
            #pragma unroll
            for (int r = 0; r < 4; ++r) {
                const float v = acc[nf][r];
                const u16 hi = f2bf(v);
                const u16 lo = f2bf(v - bf2f(hi));
                const long o = (long)(b * 2048 + tbase + r) * 64 + h;
                Hd[o] = hi; Ld[o] = lo;
            }
        } else {
            const int h = n - 128;
            const u16 p0 = f2bf(acc[nf][0]), p1 = f2bf(acc[nf][1]);
            const u16 p2 = f2bf(acc[nf][2]), p3 = f2bf(acc[nf][3]);
            *(ushort4*)&VT[(long)(b * 64 + h) * 2048 + tbase] = make_ushort4(p0, p1, p2, p3);
        }
    }
}

// ---------------------------------------------------------------------------
// stats: D_s = sum_{t>=s} exp(q_t.k_s).  Split-bf16 dots (6 mfma / 16x16 tile).
// LDS tile rows: [h_hi 64 | h_lo 64 | pad 8] bf16 (272B rows, 2-way banks).
// Grid (80, B): s-tile i, t-chunk c (<=8 t-tiles), atomicAdd partials.
// ---------------------------------------------------------------------------
__global__ __launch_bounds__(256) void stats_kernel(
    const u16* __restrict__ QH, const u16* __restrict__ QL,
    const u16* __restrict__ KH, const u16* __restrict__ KL,
    float* __restrict__ D)
{
    __shared__ u16 kt[64 * 136];
    __shared__ u16 qt[64 * 136];
    __shared__ float red[4][64];
    const int tid = threadIdx.x;
    const int w = tid >> 6, lr = tid & 15, quad = (tid >> 4) & 3;
    const int b = blockIdx.y;
    int x = blockIdx.x, i = 0;
    for (;;) { const int nc = (39 - i) >> 3; if (x < nc) break; x -= nc; ++i; }
    const int c = x;
    const int s0 = i * 64;

    #pragma unroll
    for (int it = 0; it < 2; ++it) {
        const int e = it * 256 + tid;
        const int s = e >> 3, c8 = e & 7;
        const long g = (long)(b * 2048 + s0 + s) * 64 + 8 * c8;
        *(float4*)&kt[s * 136 + 8 * c8]      = *(const float4*)&KH[g];
        *(float4*)&kt[s * 136 + 64 + 8 * c8] = *(const float4*)&KL[g];
    }

    float dsum[4] = {0.f, 0.f, 0.f, 0.f};
    const int ar = (w * 16 + lr) * 136;
    const int jt1 = min(i + 8 * c + 8, 32);
    for (int jt = i + 8 * c; jt < jt1; ++jt) {
        __syncthreads();
        #pragma unroll
        for (int it = 0; it < 2; ++it) {
            const int e = it * 256 + tid;
            const int t = e >> 3, c8 = e & 7;
            const long g = (long)(b * 2048 + jt * 64 + t) * 64 + 8 * c8;
            *(float4*)&qt[t * 136 + 8 * c8]      = *(const float4*)&QH[g];
            *(float4*)&qt[t * 136 + 64 + 8 * c8] = *(const float4*)&QL[g];
        }
        __syncthreads();

        const bf16x8 ah0 = *(const bf16x8*)&qt[ar + quad * 8];
        const bf16x8 al0 = *(const bf16x8*)&qt[ar + 64 + quad * 8];
        const bf16x8 ah1 = *(const bf16x8*)&qt[ar + 32 + quad * 8];
        const bf16x8 al1 = *(const bf16x8*)&qt[ar + 96 + quad * 8];
        #pragma unroll
        for (int nf = 0; nf < 4; ++nf) {
            const int br = (nf * 16 + lr) * 136;
            f32x4 cc = {};
            const bf16x8 bh0 = *(const bf16x8*)&kt[br + quad * 8];
            const bf16x8 bl0 = *(const bf16x8*)&kt[br + 64 + quad * 8];
            cc = MFMA(ah0, bh0, cc); cc = MFMA(ah0, bl0, cc); cc = MFMA(al0, bh0, cc);
            const bf16x8 bh1 = *(const bf16x8*)&kt[br + 32 + quad * 8];
            const bf16x8 bl1 = *(const bf16x8*)&kt[br + 96 + quad * 8];
            cc = MFMA(ah1, bh1, cc); cc = MFMA(ah1, bl1, cc); cc = MFMA(al1, bh1, cc);

            if (jt > i) {
                dsum[nf] += __expf(cc[0]) + __expf(cc[1]) + __expf(cc[2]) + __expf(cc[3]);
            } else {   // diagonal tile: include t >= s
                const int sl = nf * 16 + lr;
                #pragma unroll
                for (int r = 0; r < 4; ++r) {
                    const int tl = w * 16 + quad * 4 + r;
                    if (tl >= sl) dsum[nf] += __expf(cc[r]);
                }
            }
        }
    }

    #pragma unroll
    for (int nf = 0; nf < 4; ++nf) {
        dsum[nf] += __shfl_xor(dsum[nf], 16);
        dsum[nf] += __shfl_xor(dsum[nf], 32);
    }
    if (quad == 0) {
        #pragma unroll
        for (int nf = 0; nf < 4; ++nf) red[w][nf * 16 + lr] = dsum[nf];
    }
    __syncthreads();
    if (tid < 64)
        atomicAdd(&D[b * 2048 + s0 + tid],
                  red[0][tid] + red[1][tid] + red[2][tid] + red[3][tid]);
}

// ---------------------------------------------------------------------------
// out: per t-tile, loop s-tiles <= t.  Split-bf16 dot -> w = exp * (1/D_s)
// (masked on diag) -> bf16 into LDS wa[t][s] (A-operand layout, own-wave
// strip, no barrier needed) -> PV mfma with vT tile -> store / atomicAdd.
// ---------------------------------------------------------------------------
__global__ __launch_bounds__(256) void out_kernel(
    const u16* __restrict__ QH, const u16* __restrict__ QL,
    const u16* __restrict__ KH, const u16* __restrict__ KL,
    const u16* __restrict__ VT, const float* __restrict__ D,
    float* __restrict__ out)
{
    __shared__ u16 qt[64 * 136];
    __shared__ u16 kt[64 * 136];
    __shared__ u16 vt[64 * 72];
    __shared__ u16 wa[64 * 72];
    __shared__ float rdt[64];
    const int tid = threadIdx.x;
    const int w = tid >> 6, lr = tid & 15, quad = (tid >> 4) & 3;
    const int b = blockIdx.y;
    int x = blockIdx.x, i = 0;
    for (;;) { const int nc = (i + 8) >> 3; if (x < nc) break; x -= nc; ++i; }
    const int c = x;
    const int t0 = i * 64;

    #pragma unroll
    for (int it = 0; it < 2; ++it) {   // stage Q tile once
        const int e = it * 256 + tid;
        const int t = e >> 3, c8 = e & 7;
        const long g = (long)(b * 2048 + t0 + t) * 64 + 8 * c8;
        *(float4*)&qt[t * 136 + 8 * c8]      = *(const float4*)&QH[g];
        *(float4*)&qt[t * 136 + 64 + 8 * c8] = *(const float4*)&QL[g];
    }

    f32x4 oacc[4] = {};
    const int ar = (w * 16 + lr) * 136;
    const int js1 = min(8 * c + 8, i + 1);
    for (int js = 8 * c; js < js1; ++js) {
        const int s0 = js * 64;
        __syncthreads();
        #pragma unroll
        for (int it = 0; it < 2; ++it) {
            const int e = it * 256 + tid;
            const int s = e >> 3, c8 = e & 7;
            const long g = (long)(b * 2048 + s0 + s) * 64 + 8 * c8;
            *(float4*)&kt[s * 136 + 8 * c8]      = *(const float4*)&KH[g];
            *(float4*)&kt[s * 136 + 64 + 8 * c8] = *(const float4*)&KL[g];
        }
        #pragma unroll
        for (int it = 0; it < 2; ++it) {
            const int e = it * 256 + tid;
            const int h = e >> 3, c8 = e & 7;
            *(float4*)&vt[h * 72 + 8 * c8] =
                *(const float4*)&VT[(long)(b * 64 + h) * 2048 + s0 + 8 * c8];
        }
        if (tid < 64) rdt[tid] = 1.0f / D[b * 2048 + s0 + tid];
        __syncthreads();

        // dot phase (wave strip: t rows w*16..w*16+15)
        const bf16x8 ah0 = *(const bf16x8*)&qt[ar + quad * 8];
        const bf16x8 al0 = *(const bf16x8*)&qt[ar + 64 + quad * 8];
        const bf16x8 ah1 = *(const bf16x8*)&qt[ar + 32 + quad * 8];
        const bf16x8 al1 = *(const bf16x8*)&qt[ar + 96 + quad * 8];
        const bool diag = (js == i);
        #pragma unroll
        for (int nf = 0; nf < 4; ++nf) {
            const int br = (nf * 16 + lr) * 136;
            f32x4 cc = {};
            const bf16x8 bh0 = *(const bf16x8*)&kt[br + quad * 8];
            const bf16x8 bl0 = *(const bf16x8*)&kt[br + 64 + quad * 8];
            cc = MFMA(ah0, bh0, cc); cc = MFMA(ah0, bl0, cc); cc = MFMA(al0, bh0, cc);
            const bf16x8 bh1 = *(const bf16x8*)&kt[br + 32 + quad * 8];
            const bf16x8 bl1 = *(const bf16x8*)&kt[br + 96 + quad * 8];
            cc = MFMA(ah1, bh1, cc); cc = MFMA(ah1, bl1, cc); cc = MFMA(al1, bh1, cc);

            const int sl = nf * 16 + lr;
            const float rv = rdt[sl];
            #pragma unroll
            for (int r = 0; r < 4; ++r) {
                const int tl = w * 16 + quad * 4 + r;
                float wgt = __expf(cc[r]) * rv;
                if (diag && tl < sl) wgt = 0.f;
                wa[tl * 72 + sl] = f2bf(wgt);     // own-wave strip only
            }
        }
        // PV: A = wa strip (own rows), B = vt [h][s]
        #pragma unroll
        for (int kk = 0; kk < 2; ++kk) {
            const bf16x8 av = *(const bf16x8*)&wa[(w * 16 + lr) * 72 + kk * 32 + quad * 8];
            #pragma unroll
            for (int nf = 0; nf < 4; ++nf) {
                const bf16x8 bv = *(const bf16x8*)&vt[(nf * 16 + lr) * 72 + kk * 32 + quad * 8];
                oacc[nf] = MFMA(av, bv, oacc[nf]);
            }
        }
    }

    const bool single = (i < 8);
    #pragma unroll
    for (int nf = 0; nf < 4; ++nf) {
        const int h = nf * 16 + lr;
        #pragma unroll
        for (int r = 0; r < 4; ++r) {
            const int t = t0 + w * 16 + quad * 4 + r;
            const long o = (long)(b * 2048 + t) * 64 + h;
            if (single) out[o] = oacc[nf][r];
            else        atomicAdd(&out[o], oacc[nf][r]);
        }
    }
}

extern "C" void kernel_launch(void* const* d_in, const int* in_sizes, int n_in,
                              void* d_out, int out_size, void* d_ws, size_t ws_size,
                              hipStream_t stream)
{
    const float* idx = (const float*)d_in[0];
    const float* Wk  = (const float*)d_in[1];
    const float* Wq  = (const float*)d_in[2];
    const float* Wv  = (const float*)d_in[3];
    char* ws = (char*)d_ws;
    float* out = (float*)d_out;

    u16* WH = (u16*)(ws + WH_OFF); u16* WL = (u16*)(ws + WL_OFF);
    u16* QH = (u16*)(ws + QH_OFF); u16* QL = (u16*)(ws + QL_OFF);
    u16* KH = (u16*)(ws + KH_OFF); u16* KL = (u16*)(ws + KL_OFF);
    u16* VT = (u16*)(ws + VT_OFF);
    float* Dp = (float*)(ws + DD_OFF);

    hipMemsetAsync(out, 0, (size_t)8 * 2048 * 64 * sizeof(float), stream);
    hipMemsetAsync(Dp, 0, (size_t)8 * 2048 * sizeof(float), stream);

    wsplit_kernel<<<192, 256, 0, stream>>>(Wk, Wq, Wv, WH, WL);
    qkv_kernel<<<512, 256, 0, stream>>>(idx, WH, WL, QH, QL, KH, KL, VT);
    stats_kernel<<<dim3(80, 8), 256, 0, stream>>>(QH, QL, KH, KL, Dp);
    out_kernel<<<dim3(80, 8), 256, 0, stream>>>(QH, QL, KH, KL, VT, Dp, out);
}